// Round 2
// baseline (405.091 us; speedup 1.0000x reference)
//
#include <hip/hip_runtime.h>

// DVQ bottleneck: B=8, N=4096, D=1024, S=4, K=16, d=256, BETA=0.25
// Outputs (flat fp32 in d_out): z[8*4096*1024], ids_packed[32768] (as float),
// vq_total[1].
//
// Structure (R2): block = 256 threads = 4 waves (one per segment).
// Each wave handles 16 tokens; within the wave, lane = chunk*16 + token,
// chunk splits d=256 into 4 chunks of 64 floats. This gives 2048 blocks
// (4x R1) for latency hiding; partial fp64 dots are combined with two
// __shfl_xor rounds (offsets 16, 32).

#define D_FULL 1024
#define SEG 4
#define DSEG 256
#define KC 16
#define TPB_TOKENS 16   // tokens per block

// Prep: fp64 codebook copy + fp64 ||c||^2 per (s,k) into d_ws; zero loss slot
// (d_out is poisoned 0xAA before every timed launch).
__global__ __launch_bounds__(256) void dvq_prep(const float* __restrict__ cb,
                                                double* __restrict__ cbd,
                                                double* __restrict__ c2d,
                                                float* __restrict__ loss_out) {
    int i = threadIdx.x;
    for (int j = i; j < SEG * KC * DSEG; j += 256)
        cbd[j] = (double)cb[j];
    if (i < SEG * KC) {
        const float* p = cb + i * DSEG;
        double s = 0.0;
        for (int j = 0; j < DSEG; ++j) {
            double v = (double)p[j];
            s = fma(v, v, s);
        }
        c2d[i] = s;
    }
    if (i == 0) *loss_out = 0.0f;
}

__global__ __launch_bounds__(256) void dvq_main(const float* __restrict__ h,
                                                const float* __restrict__ cb,
                                                const double* __restrict__ cbd,
                                                const double* __restrict__ c2d,
                                                float* __restrict__ z_out,
                                                float* __restrict__ ids_out,
                                                float* __restrict__ loss_out) {
    __shared__ int ids_lds[TPB_TOKENS][SEG];
    __shared__ double red[4];

    const int i = threadIdx.x;
    const int lane = i & 63;
    const int w = i >> 6;                             // wave id == segment id
    const int s = __builtin_amdgcn_readfirstlane(w);  // wave-uniform SGPR
    const int t16 = lane & 15;                        // token within block
    const int ch = lane >> 4;                         // d-chunk 0..3 (64 floats)

    const long tok_base = (long)blockIdx.x * TPB_TOKENS;
    const long tok = tok_base + t16;

    // ---- Phase 1: fp64 partial dots over this lane's 64-float chunk ----
    const float4* zp = (const float4*)(h + tok * D_FULL + (long)s * DSEG + ch * 64);
    const double* cbs = cbd + s * (KC * DSEG) + ch * 64;  // shared by 16 lanes

    double dot[KC];
#pragma unroll
    for (int k = 0; k < KC; ++k) dot[k] = 0.0;
    double ze2 = 0.0;

#pragma unroll 4
    for (int j = 0; j < 16; ++j) {
        float4 z4 = zp[j];
        double z0 = (double)z4.x, z1 = (double)z4.y;
        double z2 = (double)z4.z, z3 = (double)z4.w;
        ze2 = fma(z0, z0, ze2);
        ze2 = fma(z1, z1, ze2);
        ze2 = fma(z2, z2, ze2);
        ze2 = fma(z3, z3, ze2);
#pragma unroll
        for (int k = 0; k < KC; ++k) {
            const double* ck = cbs + k * DSEG + j * 4;  // 16 lanes broadcast
            double a = dot[k];
            a = fma(z0, ck[0], a);
            a = fma(z1, ck[1], a);
            a = fma(z2, ck[2], a);
            a = fma(z3, ck[3], a);
            dot[k] = a;
        }
    }

    // Combine the 4 chunk partials: xor-16 then xor-32. After this every
    // lane holds the full dot[k] and ze2 for token (lane & 15).
#pragma unroll
    for (int k = 0; k < KC; ++k) {
        dot[k] += __shfl_xor(dot[k], 16, 64);
        dot[k] += __shfl_xor(dot[k], 32, 64);
    }
    ze2 += __shfl_xor(ze2, 16, 64);
    ze2 += __shfl_xor(ze2, 32, 64);

    // argmin over k; strict < keeps lowest k (jnp.argmin first-index tie-break)
    const double* c2s = c2d + s * KC;
    double best = c2s[0] - 2.0 * dot[0];
    int bk = 0;
#pragma unroll
    for (int k = 1; k < KC; ++k) {
        double sc = c2s[k] - 2.0 * dot[k];
        if (sc < best) { best = sc; bk = k; }
    }

    if (lane < TPB_TOKENS) ids_lds[t16][w] = bk;

    // min distance = ||ze||^2 + ||c||^2 - 2 ze.c  (loss contribution).
    // Each 16-lane group holds identical duplicates; reduce within width 16
    // and take lane 0's group.
    double mind = ze2 + best;
#pragma unroll
    for (int off = 8; off > 0; off >>= 1)
        mind += __shfl_down(mind, off, 16);
    if (lane == 0) red[w] = mind;

    __syncthreads();  // ids_lds + red visible to whole block

    if (i == 0) {
        double tot = red[0] + red[1] + red[2] + red[3];
        // vq_total = (1 + BETA) * sum(min_dist) / (B*N*d)
        atomicAdd(loss_out, (float)(tot * (1.25 / 8388608.0)));
    }

    // ---- Phase 2: coalesced z write (one full 1024-float row per iter) ----
#pragma unroll 4
    for (int r = 0; r < TPB_TOKENS; ++r) {
        int k = ids_lds[r][w];  // wave-uniform
        float4 v = ((const float4*)(cb + (s * KC + k) * DSEG))[lane];
        ((float4*)(z_out + (tok_base + r) * D_FULL))[i] = v;
    }

    // ---- ids_packed (as float32 values) ----
    if (i < TPB_TOKENS) {
        int p = ids_lds[i][0] + 16 * ids_lds[i][1] + 256 * ids_lds[i][2] +
                4096 * ids_lds[i][3];
        ids_out[tok_base + i] = (float)p;
    }
}

extern "C" void kernel_launch(void* const* d_in, const int* in_sizes, int n_in,
                              void* d_out, int out_size, void* d_ws, size_t ws_size,
                              hipStream_t stream) {
    const float* h  = (const float*)d_in[0];
    const float* cb = (const float*)d_in[1];

    const int n_h = in_sizes[0];          // 33554432
    const int tokens = n_h / D_FULL;      // 32768

    float* z_out    = (float*)d_out;
    float* ids_out  = z_out + (size_t)n_h;
    float* loss_out = ids_out + tokens;

    double* cbd = (double*)d_ws;                  // 16384 doubles
    double* c2d = cbd + SEG * KC * DSEG;          // 64 doubles

    dvq_prep<<<1, 256, 0, stream>>>(cb, cbd, c2d, loss_out);
    dvq_main<<<tokens / TPB_TOKENS, 256, 0, stream>>>(h, cb, cbd, c2d, z_out,
                                                      ids_out, loss_out);
}

// Round 3
// 264.562 us; speedup vs baseline: 1.5312x; 1.5312x over previous
//
#include <hip/hip_runtime.h>

// DVQ bottleneck: B=8, N=4096, D=1024, S=4, K=16, d=256, BETA=0.25
// Outputs (flat fp32 in d_out): z[8*4096*1024], ids_packed[32768] (as float),
// vq_total[1].
//
// R3 structure: block = 256 threads = 4 waves; block owns (64 tokens, 1 seg).
// lane = token (h reads per-lane rows, codebook addresses wave-uniform ->
// scalar s_loads, the property R2 broke). wave = d-chunk (64 floats each).
// Cross-wave partial-dot reduction via LDS. Grid = 2048 blocks (4x R1 waves).
// ids packed via exact float atomicAdd of bk*16^s (integers < 2^24 -> exact).

#define D_FULL 1024
#define SEG 4
#define DSEG 256
#define KC 16

// Prep (64 blocks x 256): fp64 codebook copy, fp64 ||c||^2 per (s,k),
// zero ids_out + loss (d_out/d_ws poisoned 0xAA before every timed launch).
__global__ __launch_bounds__(256) void dvq_prep(const float* __restrict__ cb,
                                                double* __restrict__ cbd,
                                                double* __restrict__ c2d,
                                                float* __restrict__ ids_out,
                                                float* __restrict__ loss_out) {
    __shared__ double ws[4];
    const int b = blockIdx.x;    // 0..63 == (s,k) pair
    const int t = threadIdx.x;
    const int lane = t & 63;
    const int w = t >> 6;

    // fp64 codebook copy: 64 blocks x 256 = 16384 elements
    cbd[b * 256 + t] = (double)cb[b * 256 + t];

    // zero ids region: 64 blocks x 512 = 32768 floats
    ids_out[b * 512 + t] = 0.0f;
    ids_out[b * 512 + 256 + t] = 0.0f;
    if (b == 0 && t == 0) *loss_out = 0.0f;

    // c2d[b] = sum over 256 elements of cb[b*256+j]^2 (fp64)
    double v = (double)cb[b * 256 + t];
    double sq = v * v;
#pragma unroll
    for (int off = 32; off > 0; off >>= 1)
        sq += __shfl_down(sq, off, 64);
    if (lane == 0) ws[w] = sq;
    __syncthreads();
    if (t == 0) c2d[b] = ws[0] + ws[1] + ws[2] + ws[3];
}

__global__ __launch_bounds__(256) void dvq_main(const float* __restrict__ h,
                                                const float* __restrict__ cb,
                                                const double* __restrict__ cbd,
                                                const double* __restrict__ c2d,
                                                float* __restrict__ z_out,
                                                float* __restrict__ ids_out,
                                                float* __restrict__ loss_out) {
    __shared__ double part[3][64][KC + 1];  // waves 1..3 partials (+1: 2-way banks)
    __shared__ int ids_lds[64];

    const int i = threadIdx.x;
    const int lane = i & 63;                           // token within block
    const int w = i >> 6;                              // wave id == d-chunk
    const int ch = __builtin_amdgcn_readfirstlane(w);  // wave-uniform SGPR

    const int s = blockIdx.x & 3;                      // segment (scalar)
    const long tok_base = (long)(blockIdx.x >> 2) * 64;
    const long tok = tok_base + lane;

    // ---- Phase 1: fp64 partial dots over this wave's 64-float chunk ----
    const float4* zp = (const float4*)(h + tok * D_FULL + (long)s * DSEG + ch * 64);
    const double* cbs = cbd + s * (KC * DSEG) + ch * 64;  // wave-uniform

    double dot[KC];
#pragma unroll
    for (int k = 0; k < KC; ++k) dot[k] = 0.0;
    double ze2 = 0.0;

#pragma unroll 4
    for (int j = 0; j < 16; ++j) {
        float4 z4 = zp[j];
        double z0 = (double)z4.x, z1 = (double)z4.y;
        double z2 = (double)z4.z, z3 = (double)z4.w;
        ze2 = fma(z0, z0, ze2);
        ze2 = fma(z1, z1, ze2);
        ze2 = fma(z2, z2, ze2);
        ze2 = fma(z3, z3, ze2);
#pragma unroll
        for (int k = 0; k < KC; ++k) {
            const double* ck = cbs + k * DSEG + j * 4;  // scalar loads
            double a = dot[k];
            a = fma(z0, ck[0], a);
            a = fma(z1, ck[1], a);
            a = fma(z2, ck[2], a);
            a = fma(z3, ck[3], a);
            dot[k] = a;
        }
    }

    // ---- Cross-wave reduction: waves 1..3 write partials, wave 0 combines --
    if (w != 0) {
        double* p = &part[w - 1][lane][0];
#pragma unroll
        for (int k = 0; k < KC; ++k) p[k] = dot[k];
        p[KC] = ze2;
    }
    __syncthreads();

    if (w == 0) {
#pragma unroll
        for (int c = 0; c < 3; ++c) {
            const double* p = &part[c][lane][0];
#pragma unroll
            for (int k = 0; k < KC; ++k) dot[k] += p[k];
            ze2 += p[KC];
        }

        // argmin; strict < keeps lowest k (jnp.argmin first-index tie-break)
        const double* c2s = c2d + s * KC;
        double best = c2s[0] - 2.0 * dot[0];
        int bk = 0;
#pragma unroll
        for (int k = 1; k < KC; ++k) {
            double sc = c2s[k] - 2.0 * dot[k];
            if (sc < best) { best = sc; bk = k; }
        }
        ids_lds[lane] = bk;

        // ids_packed contribution: bk * 16^s, exact in fp32 (<= 61440)
        atomicAdd(&ids_out[tok], (float)(bk << (4 * s)));

        // loss: min dist = ||ze||^2 + (||c||^2 - 2 ze.c), reduce 64 tokens
        double mind = ze2 + best;
#pragma unroll
        for (int off = 32; off > 0; off >>= 1)
            mind += __shfl_down(mind, off, 64);
        if (lane == 0)
            atomicAdd(loss_out, (float)(mind * (1.25 / 8388608.0)));
    }
    __syncthreads();  // ids_lds visible to all waves

    // ---- Phase 2: z write, 16 rows per wave, coalesced 1KB per row-seg ----
    const float4* cbf4 = (const float4*)cb;
#pragma unroll 4
    for (int r0 = 0; r0 < 16; ++r0) {
        int r = ch * 16 + r0;
        int k = ids_lds[r];  // wave-uniform
        float4 v = cbf4[(s * KC + k) * (DSEG / 4) + lane];
        ((float4*)(z_out + (tok_base + r) * D_FULL + (long)s * DSEG))[lane] = v;
    }
}

extern "C" void kernel_launch(void* const* d_in, const int* in_sizes, int n_in,
                              void* d_out, int out_size, void* d_ws, size_t ws_size,
                              hipStream_t stream) {
    const float* h  = (const float*)d_in[0];
    const float* cb = (const float*)d_in[1];

    const int n_h = in_sizes[0];          // 33554432
    const int tokens = n_h / D_FULL;      // 32768

    float* z_out    = (float*)d_out;
    float* ids_out  = z_out + (size_t)n_h;
    float* loss_out = ids_out + tokens;

    double* cbd = (double*)d_ws;                  // 16384 doubles
    double* c2d = cbd + SEG * KC * DSEG;          // 64 doubles

    dvq_prep<<<64, 256, 0, stream>>>(cb, cbd, c2d, ids_out, loss_out);
    dvq_main<<<(tokens / 64) * SEG, 256, 0, stream>>>(h, cb, cbd, c2d, z_out,
                                                      ids_out, loss_out);
}